// Round 1
// baseline (1923.735 us; speedup 1.0000x reference)
//
#include <hip/hip_runtime.h>
#include <math.h>

// Problem constants
#define NB   64            // batch
#define TT   2048          // time steps
#define BT   (NB*TT)       // 131072 rows
#define DIN  4
#define H0   64
#define DD   128
#define HD   256

// LIF chunking: 8 chunks of 256 steps, 64-step warmup (0.5^64 decay -> exact to fp32)
#define CHUNK 256
#define NCHUNK 8
#define WARM 64

__device__ __forceinline__ float gelu_exact(float x) {
    return 0.5f * x * (1.0f + erff(x * 0.7071067811865476f));
}

// ---------------- Projector stage 1: G = gelu(hist @ pw1 + pb1)  [BT,64] ----
__global__ void proj1_kernel(const float* __restrict__ hist, const float* __restrict__ pw1,
                             const float* __restrict__ pb1, float* __restrict__ G) {
    int tid = blockIdx.x * 256 + threadIdx.x;     // BT*64 threads
    int r = tid >> 6, j = tid & 63;
    const float* h = hist + (size_t)r * DIN;
    float acc = pb1[j];
    acc += h[0] * pw1[0*64 + j];
    acc += h[1] * pw1[1*64 + j];
    acc += h[2] * pw1[2*64 + j];
    acc += h[3] * pw1[3*64 + j];
    G[tid] = gelu_exact(acc);
}

// ---------------- Projector stage 2: X = G @ pw2 + pb2  [BT,128] ------------
// persistent blocks, pw2 (32KB) in LDS, wave=8 rows, lane=2 cols
__global__ void __launch_bounds__(512) proj2_kernel(const float* __restrict__ G,
        const float* __restrict__ pw2, const float* __restrict__ pb2,
        float* __restrict__ X) {
    __shared__ float4 Wl4[64*128/4];
    float* Wl = (float*)Wl4;
    for (int i = threadIdx.x; i < 64*128/4; i += 512)
        Wl4[i] = ((const float4*)pw2)[i];
    __syncthreads();
    int wave = threadIdx.x >> 6, lane = threadIdx.x & 63;
    float2 bv = ((const float2*)pb2)[lane];
    // tiles of 8 rows: 16384 tiles, 512 blocks * 8 waves -> 4 iterations
    for (int tile = blockIdx.x * 8 + wave; tile < BT/8; tile += 4096) {
        int rb = __builtin_amdgcn_readfirstlane(tile) * 8;
        const float* __restrict__ g0 = G + (size_t)rb * 64;
        float2 acc[8];
        #pragma unroll
        for (int r = 0; r < 8; ++r) acc[r] = make_float2(0.f, 0.f);
        #pragma unroll 8
        for (int k = 0; k < 64; ++k) {
            float2 w = ((const float2*)(Wl + k*128))[lane];
            #pragma unroll
            for (int r = 0; r < 8; ++r) {
                float xv = g0[(size_t)r*64 + k];          // wave-uniform -> s_load
                acc[r].x += xv * w.x;
                acc[r].y += xv * w.y;
            }
        }
        #pragma unroll
        for (int r = 0; r < 8; ++r) {
            float2 o; o.x = acc[r].x + bv.x; o.y = acc[r].y + bv.y;
            ((float2*)(X + (size_t)(rb + r) * 128))[lane] = o;
        }
    }
}

// ---------------- fc1 + LayerNorm: Hout = LN(X @ W1 + b1)  [BT,256] ---------
// K=128 staged in two 64KB LDS halves; wave=8 rows, lane=4 cols
__global__ void __launch_bounds__(512) fc1_kernel(const float* __restrict__ Xin,
        const float* __restrict__ W, const float* __restrict__ bias,
        const float* __restrict__ gamma, const float* __restrict__ beta,
        float* __restrict__ Hout) {
    __shared__ float4 Wl4[64*256/4];   // 64KB half
    float* Wl = (float*)Wl4;
    int wave = threadIdx.x >> 6, lane = threadIdx.x & 63;
    float4 bv  = ((const float4*)bias)[lane];
    float4 gv  = ((const float4*)gamma)[lane];
    float4 btv = ((const float4*)beta)[lane];
    for (int tile = blockIdx.x * 8 + wave; tile < BT/8; tile += 4096) {
        int rb = __builtin_amdgcn_readfirstlane(tile) * 8;
        const float* __restrict__ x0 = Xin + (size_t)rb * 128;
        float4 acc[8];
        #pragma unroll
        for (int r = 0; r < 8; ++r) acc[r] = make_float4(0.f,0.f,0.f,0.f);
        for (int half = 0; half < 2; ++half) {
            __syncthreads();   // previous use of Wl complete
            const float4* Wh = (const float4*)(W + half*64*256);
            for (int i = threadIdx.x; i < 64*256/4; i += 512) Wl4[i] = Wh[i];
            __syncthreads();
            const float* __restrict__ xh = x0 + half*64;
            #pragma unroll 4
            for (int k = 0; k < 64; ++k) {
                float4 w = ((const float4*)(Wl + k*256))[lane];
                #pragma unroll
                for (int r = 0; r < 8; ++r) {
                    float xv = xh[(size_t)r*128 + k];      // wave-uniform -> s_load
                    acc[r].x += xv * w.x; acc[r].y += xv * w.y;
                    acc[r].z += xv * w.z; acc[r].w += xv * w.w;
                }
            }
        }
        #pragma unroll
        for (int r = 0; r < 8; ++r) {
            float4 a = acc[r];
            a.x += bv.x; a.y += bv.y; a.z += bv.z; a.w += bv.w;
            float s = a.x + a.y + a.z + a.w;
            #pragma unroll
            for (int m = 1; m < 64; m <<= 1) s += __shfl_xor(s, m, 64);
            float mean = s * (1.0f/256.0f);
            float dx = a.x - mean, dy = a.y - mean, dz = a.z - mean, dw = a.w - mean;
            float q = dx*dx + dy*dy + dz*dz + dw*dw;
            #pragma unroll
            for (int m = 1; m < 64; m <<= 1) q += __shfl_xor(q, m, 64);
            float inv = 1.0f / sqrtf(q * (1.0f/256.0f) + 1e-5f);
            float4 o;
            o.x = dx*inv*gv.x + btv.x; o.y = dy*inv*gv.y + btv.y;
            o.z = dz*inv*gv.z + btv.z; o.w = dw*inv*gv.w + btv.w;
            ((float4*)(Hout + (size_t)(rb + r) * 256))[lane] = o;
        }
    }
}

// ---------------- LIF over t for H [b,t,256] -> spikes S (u8) ---------------
__global__ void lif1_kernel(const float* __restrict__ H, unsigned char* __restrict__ S) {
    int tid = blockIdx.x * 256 + threadIdx.x;     // 131072 threads
    int d = tid & 255;
    int rest = tid >> 8;
    int b = rest & 63;
    int c = rest >> 6;                             // chunk 0..7
    int t0 = c * CHUNK;
    int tw = (c == 0) ? 0 : (t0 - WARM);
    const float* __restrict__ hp = H + ((size_t)b * TT + tw) * 256 + d;
    float v = 0.f;
    #pragma unroll 8
    for (int t = tw; t < t0; ++t) {               // warmup, no writes
        float x = *hp; hp += 256;
        v += (x - v) * 0.5f;
        v = (v >= 1.0f) ? 0.f : v;
    }
    unsigned char* __restrict__ sp = S + ((size_t)b * TT + t0) * 256 + d;
    #pragma unroll 8
    for (int t = 0; t < CHUNK; ++t) {
        float x = *hp; hp += 256;
        v += (x - v) * 0.5f;
        bool s = (v >= 1.0f);
        sp[(size_t)t * 256] = s ? (unsigned char)1 : (unsigned char)0;
        v = s ? 0.f : v;
    }
}

// ---------------- fc2 + LayerNorm: Y = LN(S @ W2 + b2)  [BT,128] ------------
// spikes are binary u8 -> SGPR bit-select 1.0f/0.0f, zero-chunk skip
__global__ void __launch_bounds__(512) fc2_kernel(const unsigned char* __restrict__ S,
        const float* __restrict__ W, const float* __restrict__ bias,
        const float* __restrict__ gamma, const float* __restrict__ beta,
        float* __restrict__ Y) {
    __shared__ float4 Wl4[128*128/4];  // 64KB half
    float* Wl = (float*)Wl4;
    int wave = threadIdx.x >> 6, lane = threadIdx.x & 63;
    float2 bv  = ((const float2*)bias)[lane];
    float2 gv  = ((const float2*)gamma)[lane];
    float2 btv = ((const float2*)beta)[lane];
    for (int tile = blockIdx.x * 8 + wave; tile < BT/8; tile += 4096) {
        int rb = __builtin_amdgcn_readfirstlane(tile) * 8;
        const unsigned char* __restrict__ s0 = S + (size_t)rb * 256;
        float2 acc[8];
        #pragma unroll
        for (int r = 0; r < 8; ++r) acc[r] = make_float2(0.f, 0.f);
        for (int half = 0; half < 2; ++half) {
            __syncthreads();
            const float4* Wh = (const float4*)(W + half*128*128);
            for (int i = threadIdx.x; i < 128*128/4; i += 512) Wl4[i] = Wh[i];
            __syncthreads();
            for (int k4 = 0; k4 < 32; ++k4) {
                unsigned int sw[8], any = 0;
                #pragma unroll
                for (int r = 0; r < 8; ++r) {
                    sw[r] = *(const unsigned int*)(s0 + (size_t)r*256 + half*128 + k4*4);
                    any |= sw[r];
                }
                if (any == 0) continue;            // wave-uniform skip
                #pragma unroll
                for (int kk = 0; kk < 4; ++kk) {
                    float2 w = ((const float2*)(Wl + (k4*4 + kk)*128))[lane];
                    #pragma unroll
                    for (int r = 0; r < 8; ++r) {
                        float fs = __uint_as_float((((sw[r] >> (kk*8)) & 1u) != 0u) ? 0x3f800000u : 0u);
                        acc[r].x += fs * w.x;
                        acc[r].y += fs * w.y;
                    }
                }
            }
        }
        #pragma unroll
        for (int r = 0; r < 8; ++r) {
            float2 a = acc[r];
            a.x += bv.x; a.y += bv.y;
            float s = a.x + a.y;
            #pragma unroll
            for (int m = 1; m < 64; m <<= 1) s += __shfl_xor(s, m, 64);
            float mean = s * (1.0f/128.0f);
            float dx = a.x - mean, dy = a.y - mean;
            float q = dx*dx + dy*dy;
            #pragma unroll
            for (int m = 1; m < 64; m <<= 1) q += __shfl_xor(q, m, 64);
            float inv = 1.0f / sqrtf(q * (1.0f/128.0f) + 1e-5f);
            float2 o;
            o.x = dx*inv*gv.x + btv.x;
            o.y = dy*inv*gv.y + btv.y;
            ((float2*)(Y + (size_t)(rb + r) * 128))[lane] = o;
        }
    }
}

// ---------------- LIF2 + residual add into X; optional final output --------
__global__ void lif2_kernel(const float* __restrict__ Y, float* __restrict__ X,
                            float* __restrict__ out, int writeOut) {
    int tid = blockIdx.x * 256 + threadIdx.x;     // 65536 threads
    int n = tid & 127;
    int rest = tid >> 7;
    int b = rest & 63;
    int c = rest >> 6;                             // chunk 0..7
    int t0 = c * CHUNK;
    int tw = (c == 0) ? 0 : (t0 - WARM);
    const float* __restrict__ yp = Y + ((size_t)b * TT + tw) * 128 + n;
    float v = 0.f;
    #pragma unroll 8
    for (int t = tw; t < t0; ++t) {
        float x = *yp; yp += 128;
        v += (x - v) * 0.5f;
        v = (v >= 1.0f) ? 0.f : v;
    }
    float* __restrict__ xp = X + ((size_t)b * TT + t0) * 128 + n;
    #pragma unroll 4
    for (int t = 0; t < CHUNK; ++t) {
        float x = *yp; yp += 128;
        v += (x - v) * 0.5f;
        bool s = (v >= 1.0f);
        bool last = (writeOut != 0) && ((t0 + t) == (TT - 1));
        if (s) {
            float xv = xp[(size_t)t * 128] + 1.0f;
            xp[(size_t)t * 128] = xv;
            if (last) out[b * 128 + n] = xv;
        } else if (last) {
            out[b * 128 + n] = xp[(size_t)t * 128];
        }
        v = s ? 0.f : v;
    }
}

extern "C" void kernel_launch(void* const* d_in, const int* in_sizes, int n_in,
                              void* d_out, int out_size, void* d_ws, size_t ws_size,
                              hipStream_t stream) {
    const float* hist = (const float*)d_in[0];
    const float* pw1  = (const float*)d_in[1];
    const float* pb1  = (const float*)d_in[2];
    const float* pw2  = (const float*)d_in[3];
    const float* pb2  = (const float*)d_in[4];
    const float* fc1w = (const float*)d_in[5];
    const float* fc1b = (const float*)d_in[6];
    const float* n1g  = (const float*)d_in[7];
    const float* n1b  = (const float*)d_in[8];
    const float* fc2w = (const float*)d_in[9];
    const float* fc2b = (const float*)d_in[10];
    const float* n2g  = (const float*)d_in[11];
    const float* n2b  = (const float*)d_in[12];
    float* out = (float*)d_out;

    char* ws = (char*)d_ws;
    float* X = (float*)ws;                                   // [BT,128] f32: 64 MiB
    float* H = (float*)(ws + (size_t)67108864);              // [BT,256] f32: 128 MiB (reused as G and Y)
    unsigned char* S = (unsigned char*)(ws + (size_t)67108864 + 134217728); // [BT,256] u8: 32 MiB
    float* G = H;      // projector hidden reuses H region
    float* Y = H;      // fc2 output reuses H region (H dead after lif1)

    proj1_kernel<<<BT*64/256, 256, 0, stream>>>(hist, pw1, pb1, G);
    proj2_kernel<<<512, 512, 0, stream>>>(G, pw2, pb2, X);
    for (int i = 0; i < 4; ++i) {
        fc1_kernel<<<512, 512, 0, stream>>>(X, fc1w + (size_t)i*128*256,
                                            fc1b + i*256, n1g + i*256, n1b + i*256, H);
        lif1_kernel<<<BT/256, 256, 0, stream>>>(H, S);
        fc2_kernel<<<512, 512, 0, stream>>>(S, fc2w + (size_t)i*256*128,
                                            fc2b + i*128, n2g + i*128, n2b + i*128, Y);
        lif2_kernel<<<NB*128*NCHUNK/256, 256, 0, stream>>>(Y, X, out, (i == 3) ? 1 : 0);
    }
}